// Round 10
// baseline (92.113 us; speedup 1.0000x reference)
//
#include <hip/hip_runtime.h>

// Causal linear attention (ELU+1), chunked bf16-MFMA, 3 plain launches.
// R10 = R8 k_out (4-way row split, 512 thr — best measured) plus:
//  - causal truncation at 4-split: kceil=(rs+1)*32; K/V staging and GEMM2
//    cols + GEMM3 k-loop truncated (R9 showed 8-split truncation loses to
//    duplication; 4-split is the fetch-minimal point: 640 vs 1024 rows)
//  - register z (R9-validated): ones-B / kprev-B z-frags have identical
//    columns -> every lane holds z(row q*4+e) in elem e; no sZ, 3 syncs
//  - S_prev prefetched into VGPRs at entry, written to LDS after S2
//    (L2 latency hidden under GEMM2)
// k1/k_scan unchanged (R8-verified).  Harness floor ~47-50us (256MB ws
// poison fill + input restore) is not controllable from kernel source.

#define EPS 1e-6f

constexpr int Bc = 2;
constexpr int L  = 4096;
constexpr int D  = 128;
constexpr int C  = 128;
constexpr int NC = L / C;   // 32
constexpr int P  = 136;     // LDS row pitch (bf16), rows 16B-aligned

typedef short sh8 __attribute__((ext_vector_type(8)));
typedef float f4  __attribute__((ext_vector_type(4)));

__device__ __forceinline__ float phi(float x) {
    return x > 0.0f ? x + 1.0f : __expf(x);
}
__device__ __forceinline__ unsigned short f2bf(float f) {
    unsigned u = __float_as_uint(f);
    return (unsigned short)((u + 0x7FFFu + ((u >> 16) & 1u)) >> 16);  // RNE
}
__device__ __forceinline__ float bf2f(unsigned short h) {
    return __uint_as_float(((unsigned)h) << 16);
}
__device__ __forceinline__ unsigned packbf(float a, float b) {
    return (unsigned)f2bf(a) | ((unsigned)f2bf(b) << 16);
}
__device__ __forceinline__ sh8 splat1() {
    sh8 s;
#pragma unroll
    for (int j = 0; j < 8; ++j) s[j] = (short)0x3F80;
    return s;
}

// ---------------------------------------------------------------------------
// k1 (NC,B,2), 512 thr: S_c^T[v][i] = sum_l V[l][v] phiK[l][i] + ksum.
// Coalesced reads; transposes in LDS via swizzle. (unchanged from R8)
// ---------------------------------------------------------------------------
__global__ __launch_bounds__(512) void k1(
    const float* __restrict__ K, const float* __restrict__ V,
    unsigned short* __restrict__ SB, float* __restrict__ Ksum) {
    const int c = blockIdx.x, b = blockIdx.y, vs = blockIdx.z;
    const int tid = threadIdx.x;
    __shared__ __align__(16) unsigned short sVT[64 * P];   // V^T slice [vr][l]
    __shared__ __align__(16) unsigned short sKT[128 * P];  // phiK^T [i][l]
    const size_t base = ((size_t)b * L + (size_t)c * C) * D;

    for (int k = 0; k < 4; ++k) {
        int fi = tid + 512 * k;
        int l = fi >> 4, c4 = fi & 15;
        float4 vd = *(const float4*)(V + base + (size_t)l * D + vs * 64 + c4 * 4);
        int blk = (((l >> 3) + c4) & 15) * 8 + (l & 7);
        sVT[(c4 * 4 + 0) * P + blk] = f2bf(vd.x);
        sVT[(c4 * 4 + 1) * P + blk] = f2bf(vd.y);
        sVT[(c4 * 4 + 2) * P + blk] = f2bf(vd.z);
        sVT[(c4 * 4 + 3) * P + blk] = f2bf(vd.w);
    }
    for (int k = 0; k < 8; ++k) {
        int fi = tid + 512 * k;
        int l = fi >> 5, i4 = fi & 31;
        float4 kd = *(const float4*)(K + base + (size_t)l * D + i4 * 4);
        int blk = (((l >> 3) + i4) & 15) * 8 + (l & 7);
        sKT[(i4 * 4 + 0) * P + blk] = f2bf(phi(kd.x));
        sKT[(i4 * 4 + 1) * P + blk] = f2bf(phi(kd.y));
        sKT[(i4 * 4 + 2) * P + blk] = f2bf(phi(kd.z));
        sKT[(i4 * 4 + 3) * P + blk] = f2bf(phi(kd.w));
    }
    __syncthreads();

    const int w = tid >> 6, lane = tid & 63;
    const int r = lane & 15, q = lane >> 4;
    const int rbase = (w & 3) * 16;
    const int cbase = (w >> 2) * 64;
    const bool doK = ((w & 3) == 0);
    const sh8 ones = splat1();

    f4 acc[4], kz[4];
#pragma unroll
    for (int f = 0; f < 4; ++f) { acc[f] = {0.f,0.f,0.f,0.f}; kz[f] = {0.f,0.f,0.f,0.f}; }
#pragma unroll
    for (int ks = 0; ks < 4; ++ks) {
        int kq = ks * 4 + q;
        int vr = rbase + r;
        sh8 a = *(const sh8*)(sVT + vr * P + ((kq + (vr >> 2)) & 15) * 8);
#pragma unroll
        for (int f = 0; f < 4; ++f) {
            int ir = cbase + f * 16 + r;
            sh8 bk = *(const sh8*)(sKT + ir * P + ((kq + (ir >> 2)) & 15) * 8);
            acc[f] = __builtin_amdgcn_mfma_f32_16x16x32_bf16(a, bk, acc[f], 0, 0, 0);
            if (doK) kz[f] = __builtin_amdgcn_mfma_f32_16x16x32_bf16(ones, bk, kz[f], 0, 0, 0);
        }
    }
    unsigned short* out = SB + ((size_t)(b * NC + c)) * D * D;
#pragma unroll
    for (int f = 0; f < 4; ++f) {
        int i = cbase + f * 16 + r;
#pragma unroll
        for (int e = 0; e < 4; ++e) {
            int v = vs * 64 + rbase + q * 4 + e;
            out[(size_t)v * D + i] = f2bf(acc[f][e]);
        }
    }
    if (doK && q == 0 && vs == 0) {
#pragma unroll
        for (int f = 0; f < 4; ++f)
            Ksum[((size_t)(b * NC + c)) * D + cbase + f * 16 + r] = kz[f][0];
    }
}

// ---------------------------------------------------------------------------
// k_scan: exclusive prefix over chunks, prefetch-all-32. (unchanged from R8)
// ---------------------------------------------------------------------------
__global__ __launch_bounds__(256) void k_scan(unsigned short* __restrict__ SB,
                                              float* __restrict__ Ksum) {
    const int SD = D * D;
    int idx = blockIdx.x * 256 + threadIdx.x;
    if (idx < Bc * SD) {
        int b = idx / SD, e = idx % SD;
        size_t off0 = (size_t)b * NC * SD + e;
        unsigned short vals[NC];
#pragma unroll
        for (int c = 0; c < NC; ++c) vals[c] = SB[off0 + (size_t)c * SD];
        float run = 0.0f;
#pragma unroll
        for (int c = 0; c < NC; ++c) {
            SB[off0 + (size_t)c * SD] = f2bf(run);
            run += bf2f(vals[c]);
        }
    } else if (idx < Bc * SD + Bc * D) {
        int rr = idx - Bc * SD;
        int b = rr >> 7, i = rr & 127;
        size_t off0 = (size_t)b * NC * D + i;
        float vals[NC];
#pragma unroll
        for (int c = 0; c < NC; ++c) vals[c] = Ksum[off0 + (size_t)c * D];
        float run = 0.0f;
#pragma unroll
        for (int c = 0; c < NC; ++c) {
            Ksum[off0 + (size_t)c * D] = run;
            run += vals[c];
        }
    }
}

// ---------------------------------------------------------------------------
// k_out (NC,B,4), rows split 4x32, 512 thr (8 waves: rbase=(w&1)*16,
// col quarter cq=w>>1).  Causal truncation kceil=(rs+1)*32; register z;
// S_prev prefetched to VGPRs.  3 syncs.  LDS 87 KB.
// ---------------------------------------------------------------------------
__global__ __launch_bounds__(512) void k_out(
    const float* __restrict__ Q, const float* __restrict__ K,
    const float* __restrict__ V, const unsigned short* __restrict__ SB,
    const float* __restrict__ Ksum, float* __restrict__ Out) {
    const int c = blockIdx.x, b = blockIdx.y, rs = blockIdx.z;  // rs 0..3
    const int tid = threadIdx.x;
    __shared__ __align__(16) unsigned short sQ[32 * P];    // phiQ rows
    __shared__ __align__(16) unsigned short sK[128 * P];   // phiK rows -> S^T
    __shared__ __align__(16) unsigned short sVT[128 * P];  // V^T swizzled
    __shared__ __align__(16) unsigned short sAm[32 * P];   // masked A
    const size_t base  = ((size_t)b * L + (size_t)c * C) * D;
    const size_t tbase = ((size_t)(b * NC + c)) * (size_t)D * D;
    const size_t kb    = ((size_t)(b * NC + c)) * D;
    const int kceil = (rs + 1) * 32;       // staged/compute K,V rows

    // S_prev^T prefetch into registers (independent of staging; L2 latency
    // hides under staging + GEMM2)
    uint4 sreg[4];
    {
        const uint4* sg = (const uint4*)(SB + tbase);
#pragma unroll
        for (int k = 0; k < 4; ++k) sreg[k] = sg[tid + 512 * k];
    }

    // phiQ rows rs*32..+32 (1024 float4)
    for (int k = 0; k < 2; ++k) {
        int fi = tid + 512 * k;
        int row = fi >> 5, c4 = fi & 31;
        float4 qd = *(const float4*)(Q + base + (size_t)(rs * 32 + row) * D + c4 * 4);
        uint2 pq; pq.x = packbf(phi(qd.x), phi(qd.y)); pq.y = packbf(phi(qd.z), phi(qd.w));
        *(uint2*)(sQ + row * P + c4 * 4) = pq;
    }
    // phiK rows [0, kceil) (kceil*32 float4, coalesced)
    for (int fi = tid; fi < kceil * 32; fi += 512) {
        int row = fi >> 5, c4 = fi & 31;
        float4 kd = *(const float4*)(K + base + (size_t)row * D + c4 * 4);
        uint2 pk; pk.x = packbf(phi(kd.x), phi(kd.y)); pk.y = packbf(phi(kd.z), phi(kd.w));
        *(uint2*)(sK + row * P + c4 * 4) = pk;
    }
    // V^T swizzled, l in [0, kceil)
    for (int fi = tid; fi < kceil * 32; fi += 512) {
        int l = fi >> 5, i4 = fi & 31;
        float4 vd = *(const float4*)(V + base + (size_t)l * D + i4 * 4);
        int blk = (((l >> 3) + i4) & 15) * 8 + (l & 7);
        sVT[(i4 * 4 + 0) * P + blk] = f2bf(vd.x);
        sVT[(i4 * 4 + 1) * P + blk] = f2bf(vd.y);
        sVT[(i4 * 4 + 2) * P + blk] = f2bf(vd.z);
        sVT[(i4 * 4 + 3) * P + blk] = f2bf(vd.w);
    }
    __syncthreads();                       // S1

    const int w = tid >> 6, lane = tid & 63;
    const int r = lane & 15, q = lane >> 4;
    const int rbase = (w & 1) * 16;
    const int cq = w >> 1, cbase = cq * 32;
    const int flim = (cq <= rs) ? 2 : 0;   // GEMM2 col-frags below kceil

    // kprev B-frags for GEMM4 z (r-invariant; every wave; L2-hot)
    sh8 bzk[4];
#pragma unroll
    for (int ks = 0; ks < 4; ++ks) {
        float4 f0 = *(const float4*)(Ksum + kb + ks * 32 + q * 8);
        float4 f1 = *(const float4*)(Ksum + kb + ks * 32 + q * 8 + 4);
        sh8 t;
        t[0] = (short)f2bf(f0.x); t[1] = (short)f2bf(f0.y);
        t[2] = (short)f2bf(f0.z); t[3] = (short)f2bf(f0.w);
        t[4] = (short)f2bf(f1.x); t[5] = (short)f2bf(f1.y);
        t[6] = (short)f2bf(f1.z); t[7] = (short)f2bf(f1.w);
        bzk[ks] = t;
    }

    // ---- GEMM2: A = phiQ phiK^T (cols truncated to kceil) ----
    f4 a2[2];
    a2[0] = {0.f,0.f,0.f,0.f}; a2[1] = {0.f,0.f,0.f,0.f};
#pragma unroll
    for (int ks = 0; ks < 4; ++ks) {
        sh8 a = *(const sh8*)(sQ + (rbase + r) * P + ks * 32 + q * 8);
        for (int f = 0; f < flim; ++f) {
            sh8 bb = *(const sh8*)(sK + (cbase + f * 16 + r) * P + ks * 32 + q * 8);
            a2[f] = __builtin_amdgcn_mfma_f32_16x16x32_bf16(a, bb, a2[f], 0, 0, 0);
        }
    }
    for (int f = 0; f < flim; ++f) {       // causal mask -> sAm bf16
        int j = cbase + f * 16 + r;
#pragma unroll
        for (int e = 0; e < 4; ++e) {
            int lr = rbase + q * 4 + e;
            sAm[lr * P + j] = f2bf((j <= rs * 32 + lr) ? a2[f][e] : 0.f);
        }
    }
    __syncthreads();                       // S2: sAm ready, sK reads done

    // write prefetched S_prev^T into sK (regs -> LDS, no global latency)
#pragma unroll
    for (int k = 0; k < 4; ++k) {
        int f2 = tid + 512 * k;
        *(uint4*)(sK + (f2 >> 4) * P + (f2 & 15) * 8) = sreg[k];
    }

    // ---- GEMM3: acc = Am @ V, k-loop truncated to kceil; + rowsum z ----
    f4 acc[2], zacc = {0.f,0.f,0.f,0.f};
    acc[0] = {0.f,0.f,0.f,0.f}; acc[1] = {0.f,0.f,0.f,0.f};
    const sh8 ones = splat1();
    for (int ks = 0; ks <= rs; ++ks) {     // kceil/32 = rs+1 iterations
        int kq = ks * 4 + q;
        sh8 am = *(const sh8*)(sAm + (rbase + r) * P + ks * 32 + q * 8);
#pragma unroll
        for (int f = 0; f < 2; ++f) {
            int vr = cbase + f * 16 + r;
            sh8 bv = *(const sh8*)(sVT + vr * P + ((kq + (vr >> 2)) & 15) * 8);
            acc[f] = __builtin_amdgcn_mfma_f32_16x16x32_bf16(am, bv, acc[f], 0, 0, 0);
        }
        zacc = __builtin_amdgcn_mfma_f32_16x16x32_bf16(am, ones, zacc, 0, 0, 0);
    }
    __syncthreads();                       // S3: sK = S^T ready

    // ---- GEMM4: acc += phiQ @ S_prev (full K=128); + kprev z ----
#pragma unroll
    for (int ks = 0; ks < 4; ++ks) {
        sh8 a = *(const sh8*)(sQ + (rbase + r) * P + ks * 32 + q * 8);
#pragma unroll
        for (int f = 0; f < 2; ++f) {
            sh8 bs = *(const sh8*)(sK + (cbase + f * 16 + r) * P + ks * 32 + q * 8);
            acc[f] = __builtin_amdgcn_mfma_f32_16x16x32_bf16(a, bs, acc[f], 0, 0, 0);
        }
        zacc = __builtin_amdgcn_mfma_f32_16x16x32_bf16(a, bzk[ks], zacc, 0, 0, 0);
    }

    // ---- normalize + store: zacc[e] = z(row rbase+q*4+e) in every lane ----
#pragma unroll
    for (int e = 0; e < 4; ++e) {
        int lr = rbase + q * 4 + e;
        float rz = 1.0f / (zacc[e] + EPS);
#pragma unroll
        for (int f = 0; f < 2; ++f) {
            int v = cbase + f * 16 + r;
            Out[base + (size_t)(rs * 32 + lr) * D + v] = acc[f][e] * rz;
        }
    }
}

extern "C" void kernel_launch(void* const* d_in, const int* in_sizes, int n_in,
                              void* d_out, int out_size, void* d_ws, size_t ws_size,
                              hipStream_t stream) {
    const float* Q = (const float*)d_in[0];
    const float* K = (const float*)d_in[1];
    const float* V = (const float*)d_in[2];
    float* Out = (float*)d_out;
    unsigned short* SBw = (unsigned short*)d_ws;                        // 2 MB
    float* Ksum = (float*)((char*)d_ws + (size_t)Bc * NC * D * D * 2);  // 32 KB

    k1<<<dim3(NC, Bc, 2), 512, 0, stream>>>(K, V, SBw, Ksum);
    int total = Bc * D * D + Bc * D;
    k_scan<<<dim3((total + 255) / 256), 256, 0, stream>>>(SBw, Ksum);
    k_out<<<dim3(NC, Bc, 4), 512, 0, stream>>>(Q, K, V, SBw, Ksum, Out);
}

// Round 11
// 81.651 us; speedup vs baseline: 1.1281x; 1.1281x over previous
//
#include <hip/hip_runtime.h>

// Causal linear attention (ELU+1), chunked bf16-MFMA, 3 plain launches.
// R11 = R8 k1/k_scan + restructured k_out ("direct-frag"):
//  - Q A-frags loaded once to registers (phi once), reused GEMM2+GEMM4
//  - GEMM2 B-frags (phiK) loaded direct from global K (k-contig 32B/lane,
//    16 rows x 128B fully-used lines), phi in regs -> no sK staging
//  - GEMM4 B-frags (S_prev^T) loaded direct from SB bf16 (16B/lane dwordx4,
//    perfectly coalesced, no conversion) -> no S^T restage
//  - LDS only sVT (true transpose) + sAm: 118 KB -> 43.5 KB; syncs 4 -> 1
//  - register z (R9/R10-validated): ones-B / kprev-B z-frag columns are
//    identical -> zacc[e] = z(row rbase+q*4+e) in every lane
// R10 lesson: grid==CU count -> only critical-path cost matters; fixed
// unrolled staging loops (no variable bounds).
// Harness floor ~47-50us (256MB ws poison fill + input restore).

#define EPS 1e-6f

constexpr int Bc = 2;
constexpr int L  = 4096;
constexpr int D  = 128;
constexpr int C  = 128;
constexpr int NC = L / C;   // 32
constexpr int P  = 136;     // LDS row pitch (bf16), rows 16B-aligned

typedef short sh8 __attribute__((ext_vector_type(8)));
typedef float f4  __attribute__((ext_vector_type(4)));

__device__ __forceinline__ float phi(float x) {
    return x > 0.0f ? x + 1.0f : __expf(x);
}
__device__ __forceinline__ unsigned short f2bf(float f) {
    unsigned u = __float_as_uint(f);
    return (unsigned short)((u + 0x7FFFu + ((u >> 16) & 1u)) >> 16);  // RNE
}
__device__ __forceinline__ float bf2f(unsigned short h) {
    return __uint_as_float(((unsigned)h) << 16);
}
__device__ __forceinline__ unsigned packbf(float a, float b) {
    return (unsigned)f2bf(a) | ((unsigned)f2bf(b) << 16);
}
__device__ __forceinline__ sh8 splat1() {
    sh8 s;
#pragma unroll
    for (int j = 0; j < 8; ++j) s[j] = (short)0x3F80;
    return s;
}
// load 8 f32 from p, apply phi, pack to sh8 (A/B fragment)
__device__ __forceinline__ sh8 ldphi8(const float* p) {
    float4 f0 = *(const float4*)(p);
    float4 f1 = *(const float4*)(p + 4);
    sh8 t;
    t[0] = (short)f2bf(phi(f0.x)); t[1] = (short)f2bf(phi(f0.y));
    t[2] = (short)f2bf(phi(f0.z)); t[3] = (short)f2bf(phi(f0.w));
    t[4] = (short)f2bf(phi(f1.x)); t[5] = (short)f2bf(phi(f1.y));
    t[6] = (short)f2bf(phi(f1.z)); t[7] = (short)f2bf(phi(f1.w));
    return t;
}

// ---------------------------------------------------------------------------
// k1 (NC,B,2), 512 thr: S_c^T[v][i] = sum_l V[l][v] phiK[l][i] + ksum.
// Coalesced reads; transposes in LDS via swizzle. (unchanged from R8)
// ---------------------------------------------------------------------------
__global__ __launch_bounds__(512) void k1(
    const float* __restrict__ K, const float* __restrict__ V,
    unsigned short* __restrict__ SB, float* __restrict__ Ksum) {
    const int c = blockIdx.x, b = blockIdx.y, vs = blockIdx.z;
    const int tid = threadIdx.x;
    __shared__ __align__(16) unsigned short sVT[64 * P];   // V^T slice [vr][l]
    __shared__ __align__(16) unsigned short sKT[128 * P];  // phiK^T [i][l]
    const size_t base = ((size_t)b * L + (size_t)c * C) * D;

    for (int k = 0; k < 4; ++k) {
        int fi = tid + 512 * k;
        int l = fi >> 4, c4 = fi & 15;
        float4 vd = *(const float4*)(V + base + (size_t)l * D + vs * 64 + c4 * 4);
        int blk = (((l >> 3) + c4) & 15) * 8 + (l & 7);
        sVT[(c4 * 4 + 0) * P + blk] = f2bf(vd.x);
        sVT[(c4 * 4 + 1) * P + blk] = f2bf(vd.y);
        sVT[(c4 * 4 + 2) * P + blk] = f2bf(vd.z);
        sVT[(c4 * 4 + 3) * P + blk] = f2bf(vd.w);
    }
    for (int k = 0; k < 8; ++k) {
        int fi = tid + 512 * k;
        int l = fi >> 5, i4 = fi & 31;
        float4 kd = *(const float4*)(K + base + (size_t)l * D + i4 * 4);
        int blk = (((l >> 3) + i4) & 15) * 8 + (l & 7);
        sKT[(i4 * 4 + 0) * P + blk] = f2bf(phi(kd.x));
        sKT[(i4 * 4 + 1) * P + blk] = f2bf(phi(kd.y));
        sKT[(i4 * 4 + 2) * P + blk] = f2bf(phi(kd.z));
        sKT[(i4 * 4 + 3) * P + blk] = f2bf(phi(kd.w));
    }
    __syncthreads();

    const int w = tid >> 6, lane = tid & 63;
    const int r = lane & 15, q = lane >> 4;
    const int rbase = (w & 3) * 16;
    const int cbase = (w >> 2) * 64;
    const bool doK = ((w & 3) == 0);
    const sh8 ones = splat1();

    f4 acc[4], kz[4];
#pragma unroll
    for (int f = 0; f < 4; ++f) { acc[f] = {0.f,0.f,0.f,0.f}; kz[f] = {0.f,0.f,0.f,0.f}; }
#pragma unroll
    for (int ks = 0; ks < 4; ++ks) {
        int kq = ks * 4 + q;
        int vr = rbase + r;
        sh8 a = *(const sh8*)(sVT + vr * P + ((kq + (vr >> 2)) & 15) * 8);
#pragma unroll
        for (int f = 0; f < 4; ++f) {
            int ir = cbase + f * 16 + r;
            sh8 bk = *(const sh8*)(sKT + ir * P + ((kq + (ir >> 2)) & 15) * 8);
            acc[f] = __builtin_amdgcn_mfma_f32_16x16x32_bf16(a, bk, acc[f], 0, 0, 0);
            if (doK) kz[f] = __builtin_amdgcn_mfma_f32_16x16x32_bf16(ones, bk, kz[f], 0, 0, 0);
        }
    }
    unsigned short* out = SB + ((size_t)(b * NC + c)) * D * D;
#pragma unroll
    for (int f = 0; f < 4; ++f) {
        int i = cbase + f * 16 + r;
#pragma unroll
        for (int e = 0; e < 4; ++e) {
            int v = vs * 64 + rbase + q * 4 + e;
            out[(size_t)v * D + i] = f2bf(acc[f][e]);
        }
    }
    if (doK && q == 0 && vs == 0) {
#pragma unroll
        for (int f = 0; f < 4; ++f)
            Ksum[((size_t)(b * NC + c)) * D + cbase + f * 16 + r] = kz[f][0];
    }
}

// ---------------------------------------------------------------------------
// k_scan: exclusive prefix over chunks, prefetch-all-32. (unchanged from R8)
// ---------------------------------------------------------------------------
__global__ __launch_bounds__(256) void k_scan(unsigned short* __restrict__ SB,
                                              float* __restrict__ Ksum) {
    const int SD = D * D;
    int idx = blockIdx.x * 256 + threadIdx.x;
    if (idx < Bc * SD) {
        int b = idx / SD, e = idx % SD;
        size_t off0 = (size_t)b * NC * SD + e;
        unsigned short vals[NC];
#pragma unroll
        for (int c = 0; c < NC; ++c) vals[c] = SB[off0 + (size_t)c * SD];
        float run = 0.0f;
#pragma unroll
        for (int c = 0; c < NC; ++c) {
            SB[off0 + (size_t)c * SD] = f2bf(run);
            run += bf2f(vals[c]);
        }
    } else if (idx < Bc * SD + Bc * D) {
        int rr = idx - Bc * SD;
        int b = rr >> 7, i = rr & 127;
        size_t off0 = (size_t)b * NC * D + i;
        float vals[NC];
#pragma unroll
        for (int c = 0; c < NC; ++c) vals[c] = Ksum[off0 + (size_t)c * D];
        float run = 0.0f;
#pragma unroll
        for (int c = 0; c < NC; ++c) {
            Ksum[off0 + (size_t)c * D] = run;
            run += vals[c];
        }
    }
}

// ---------------------------------------------------------------------------
// k_out (NC,B,4), rows split 4x32, 512 thr (8 waves: rbase=(w&1)*16,
// col quarter cq=w>>1).  Direct-frag loads for Q/K/S_prev; LDS only for
// V^T (swizzled) + sAm.  ONE __syncthreads.  LDS 43.5 KB.
// ---------------------------------------------------------------------------
__global__ __launch_bounds__(512) void k_out(
    const float* __restrict__ Q, const float* __restrict__ K,
    const float* __restrict__ V, const unsigned short* __restrict__ SB,
    const float* __restrict__ Ksum, float* __restrict__ Out) {
    const int c = blockIdx.x, b = blockIdx.y, rs = blockIdx.z;  // rs 0..3
    const int tid = threadIdx.x;
    __shared__ __align__(16) unsigned short sVT[128 * P];  // V^T swizzled
    __shared__ __align__(16) unsigned short sAm[32 * P];   // masked A
    const size_t base  = ((size_t)b * L + (size_t)c * C) * D;
    const size_t tbase = ((size_t)(b * NC + c)) * (size_t)D * D;
    const size_t kb    = ((size_t)(b * NC + c)) * D;

    const int w = tid >> 6, lane = tid & 63;
    const int r = lane & 15, q = lane >> 4;
    const int rbase = (w & 1) * 16;
    const int cq = w >> 1, cbase = cq * 32;

    // ---- Q A-frags to registers (phi once; reused GEMM2 + GEMM4) ----
    sh8 aq[4];
    {
        const float* qrow = Q + base + (size_t)(rs * 32 + rbase + r) * D;
#pragma unroll
        for (int ks = 0; ks < 4; ++ks) aq[ks] = ldphi8(qrow + ks * 32 + q * 8);
    }

    // ---- stage sVT (V^T swizzled), 4096 float4 coalesced; overlaps GEMM2's
    // global-frag loads (no dependency until sync) ----
#pragma unroll
    for (int k = 0; k < 8; ++k) {
        int fi = tid + 512 * k;
        int l = fi >> 5, i4 = fi & 31;
        float4 vd = *(const float4*)(V + base + (size_t)l * D + i4 * 4);
        int blk = (((l >> 3) + i4) & 15) * 8 + (l & 7);
        sVT[(i4 * 4 + 0) * P + blk] = f2bf(vd.x);
        sVT[(i4 * 4 + 1) * P + blk] = f2bf(vd.y);
        sVT[(i4 * 4 + 2) * P + blk] = f2bf(vd.z);
        sVT[(i4 * 4 + 3) * P + blk] = f2bf(vd.w);
    }

    // ---- GEMM2: A = phiQ phiK^T, B-frags direct from global K ----
    f4 a2[2];
    a2[0] = {0.f,0.f,0.f,0.f}; a2[1] = {0.f,0.f,0.f,0.f};
    {
        const float* krow0 = K + base + (size_t)(cbase + r) * D;
        const float* krow1 = K + base + (size_t)(cbase + 16 + r) * D;
#pragma unroll
        for (int ks = 0; ks < 4; ++ks) {
            sh8 b0 = ldphi8(krow0 + ks * 32 + q * 8);
            sh8 b1 = ldphi8(krow1 + ks * 32 + q * 8);
            a2[0] = __builtin_amdgcn_mfma_f32_16x16x32_bf16(aq[ks], b0, a2[0], 0, 0, 0);
            a2[1] = __builtin_amdgcn_mfma_f32_16x16x32_bf16(aq[ks], b1, a2[1], 0, 0, 0);
        }
    }
    // causal mask -> sAm bf16
#pragma unroll
    for (int f = 0; f < 2; ++f) {
        int j = cbase + f * 16 + r;
#pragma unroll
        for (int e = 0; e < 4; ++e) {
            int lr = rbase + q * 4 + e;
            sAm[lr * P + j] = f2bf((j <= rs * 32 + lr) ? a2[f][e] : 0.f);
        }
    }
    __syncthreads();                       // the ONLY sync: sVT + sAm ready

    // ---- GEMM3: acc = Am @ V (+ rowsum z via ones-B) ----
    f4 acc[2], zacc = {0.f,0.f,0.f,0.f};
    acc[0] = {0.f,0.f,0.f,0.f}; acc[1] = {0.f,0.f,0.f,0.f};
    const sh8 ones = splat1();
#pragma unroll
    for (int ks = 0; ks < 4; ++ks) {
        int kq = ks * 4 + q;
        sh8 am = *(const sh8*)(sAm + (rbase + r) * P + ks * 32 + q * 8);
#pragma unroll
        for (int f = 0; f < 2; ++f) {
            int vr = cbase + f * 16 + r;
            sh8 bv = *(const sh8*)(sVT + vr * P + ((kq + (vr >> 2)) & 15) * 8);
            acc[f] = __builtin_amdgcn_mfma_f32_16x16x32_bf16(am, bv, acc[f], 0, 0, 0);
        }
        zacc = __builtin_amdgcn_mfma_f32_16x16x32_bf16(am, ones, zacc, 0, 0, 0);
    }

    // ---- GEMM4: acc += phiQ @ S_prev, B-frags direct from SB (bf16, no
    // conversion, 16B/lane dwordx4); + kprev z ----
    {
        const unsigned short* srow0 = SB + tbase + (size_t)(cbase + r) * D;
        const unsigned short* srow1 = SB + tbase + (size_t)(cbase + 16 + r) * D;
#pragma unroll
        for (int ks = 0; ks < 4; ++ks) {
            sh8 bs0 = *(const sh8*)(srow0 + ks * 32 + q * 8);
            sh8 bs1 = *(const sh8*)(srow1 + ks * 32 + q * 8);
            // kprev B-frag (r-invariant, L2-hot)
            float4 f0 = *(const float4*)(Ksum + kb + ks * 32 + q * 8);
            float4 f1 = *(const float4*)(Ksum + kb + ks * 32 + q * 8 + 4);
            sh8 bz;
            bz[0] = (short)f2bf(f0.x); bz[1] = (short)f2bf(f0.y);
            bz[2] = (short)f2bf(f0.z); bz[3] = (short)f2bf(f0.w);
            bz[4] = (short)f2bf(f1.x); bz[5] = (short)f2bf(f1.y);
            bz[6] = (short)f2bf(f1.z); bz[7] = (short)f2bf(f1.w);
            acc[0] = __builtin_amdgcn_mfma_f32_16x16x32_bf16(aq[ks], bs0, acc[0], 0, 0, 0);
            acc[1] = __builtin_amdgcn_mfma_f32_16x16x32_bf16(aq[ks], bs1, acc[1], 0, 0, 0);
            zacc   = __builtin_amdgcn_mfma_f32_16x16x32_bf16(aq[ks], bz, zacc, 0, 0, 0);
        }
    }

    // ---- normalize + store: zacc[e] = z(row rbase+q*4+e) in every lane ----
#pragma unroll
    for (int e = 0; e < 4; ++e) {
        int lr = rbase + q * 4 + e;
        float rz = 1.0f / (zacc[e] + EPS);
#pragma unroll
        for (int f = 0; f < 2; ++f) {
            int v = cbase + f * 16 + r;
            Out[base + (size_t)(rs * 32 + lr) * D + v] = acc[f][e] * rz;
        }
    }
}

extern "C" void kernel_launch(void* const* d_in, const int* in_sizes, int n_in,
                              void* d_out, int out_size, void* d_ws, size_t ws_size,
                              hipStream_t stream) {
    const float* Q = (const float*)d_in[0];
    const float* K = (const float*)d_in[1];
    const float* V = (const float*)d_in[2];
    float* Out = (float*)d_out;
    unsigned short* SBw = (unsigned short*)d_ws;                        // 2 MB
    float* Ksum = (float*)((char*)d_ws + (size_t)Bc * NC * D * D * 2);  // 32 KB

    k1<<<dim3(NC, Bc, 2), 512, 0, stream>>>(K, V, SBw, Ksum);
    int total = Bc * D * D + Bc * D;
    k_scan<<<dim3((total + 255) / 256), 256, 0, stream>>>(SBw, Ksum);
    k_out<<<dim3(NC, Bc, 4), 512, 0, stream>>>(Q, K, V, SBw, Ksum, Out);
}

// Round 12
// 80.119 us; speedup vs baseline: 1.1497x; 1.0191x over previous
//
#include <hip/hip_runtime.h>

// Causal linear attention (ELU+1), chunked bf16-MFMA, 3 plain launches.
// R12 = consolidation: R8's k_out skeleton (LDS-staged phiK for GEMM2 —
// MFMA feeds from ~120cyc ds_read_b128, not ~200-900cyc global) + the
// validated wins from R9-R11:
//  - phiQ A-frags in registers, loaded once, reused GEMM2+GEMM4 (R11)
//  - GEMM4 B-frags direct from SB bf16 (16B/lane dwordx4) -> no S^T
//    restage, no S3 sync (R11)
//  - register z: ones-B / kprev-B z-frag columns identical -> zacc[e] =
//    z(row rbase+q*4+e) in every lane; no sZ, no final sync (R9-R11)
// Syncs 4 -> 2.  k1/k_scan unchanged (R8-proven).
// Fill-noise note: harness 256MB ws poison fill varies 40.5-47us run-to-run
// (~±4us on totals) — compare rounds accordingly.

#define EPS 1e-6f

constexpr int Bc = 2;
constexpr int L  = 4096;
constexpr int D  = 128;
constexpr int C  = 128;
constexpr int NC = L / C;   // 32
constexpr int P  = 136;     // LDS row pitch (bf16), rows 16B-aligned

typedef short sh8 __attribute__((ext_vector_type(8)));
typedef float f4  __attribute__((ext_vector_type(4)));

__device__ __forceinline__ float phi(float x) {
    return x > 0.0f ? x + 1.0f : __expf(x);
}
__device__ __forceinline__ unsigned short f2bf(float f) {
    unsigned u = __float_as_uint(f);
    return (unsigned short)((u + 0x7FFFu + ((u >> 16) & 1u)) >> 16);  // RNE
}
__device__ __forceinline__ float bf2f(unsigned short h) {
    return __uint_as_float(((unsigned)h) << 16);
}
__device__ __forceinline__ unsigned packbf(float a, float b) {
    return (unsigned)f2bf(a) | ((unsigned)f2bf(b) << 16);
}
__device__ __forceinline__ sh8 splat1() {
    sh8 s;
#pragma unroll
    for (int j = 0; j < 8; ++j) s[j] = (short)0x3F80;
    return s;
}
// load 8 f32, apply phi, pack to sh8 fragment
__device__ __forceinline__ sh8 ldphi8(const float* p) {
    float4 f0 = *(const float4*)(p);
    float4 f1 = *(const float4*)(p + 4);
    sh8 t;
    t[0] = (short)f2bf(phi(f0.x)); t[1] = (short)f2bf(phi(f0.y));
    t[2] = (short)f2bf(phi(f0.z)); t[3] = (short)f2bf(phi(f0.w));
    t[4] = (short)f2bf(phi(f1.x)); t[5] = (short)f2bf(phi(f1.y));
    t[6] = (short)f2bf(phi(f1.z)); t[7] = (short)f2bf(phi(f1.w));
    return t;
}

// ---------------------------------------------------------------------------
// k1 (NC,B,2), 512 thr: S_c^T[v][i] = sum_l V[l][v] phiK[l][i] + ksum.
// Coalesced reads; transposes in LDS via swizzle. (unchanged from R8)
// ---------------------------------------------------------------------------
__global__ __launch_bounds__(512) void k1(
    const float* __restrict__ K, const float* __restrict__ V,
    unsigned short* __restrict__ SB, float* __restrict__ Ksum) {
    const int c = blockIdx.x, b = blockIdx.y, vs = blockIdx.z;
    const int tid = threadIdx.x;
    __shared__ __align__(16) unsigned short sVT[64 * P];   // V^T slice [vr][l]
    __shared__ __align__(16) unsigned short sKT[128 * P];  // phiK^T [i][l]
    const size_t base = ((size_t)b * L + (size_t)c * C) * D;

    for (int k = 0; k < 4; ++k) {
        int fi = tid + 512 * k;
        int l = fi >> 4, c4 = fi & 15;
        float4 vd = *(const float4*)(V + base + (size_t)l * D + vs * 64 + c4 * 4);
        int blk = (((l >> 3) + c4) & 15) * 8 + (l & 7);
        sVT[(c4 * 4 + 0) * P + blk] = f2bf(vd.x);
        sVT[(c4 * 4 + 1) * P + blk] = f2bf(vd.y);
        sVT[(c4 * 4 + 2) * P + blk] = f2bf(vd.z);
        sVT[(c4 * 4 + 3) * P + blk] = f2bf(vd.w);
    }
    for (int k = 0; k < 8; ++k) {
        int fi = tid + 512 * k;
        int l = fi >> 5, i4 = fi & 31;
        float4 kd = *(const float4*)(K + base + (size_t)l * D + i4 * 4);
        int blk = (((l >> 3) + i4) & 15) * 8 + (l & 7);
        sKT[(i4 * 4 + 0) * P + blk] = f2bf(phi(kd.x));
        sKT[(i4 * 4 + 1) * P + blk] = f2bf(phi(kd.y));
        sKT[(i4 * 4 + 2) * P + blk] = f2bf(phi(kd.z));
        sKT[(i4 * 4 + 3) * P + blk] = f2bf(phi(kd.w));
    }
    __syncthreads();

    const int w = tid >> 6, lane = tid & 63;
    const int r = lane & 15, q = lane >> 4;
    const int rbase = (w & 3) * 16;
    const int cbase = (w >> 2) * 64;
    const bool doK = ((w & 3) == 0);
    const sh8 ones = splat1();

    f4 acc[4], kz[4];
#pragma unroll
    for (int f = 0; f < 4; ++f) { acc[f] = {0.f,0.f,0.f,0.f}; kz[f] = {0.f,0.f,0.f,0.f}; }
#pragma unroll
    for (int ks = 0; ks < 4; ++ks) {
        int kq = ks * 4 + q;
        int vr = rbase + r;
        sh8 a = *(const sh8*)(sVT + vr * P + ((kq + (vr >> 2)) & 15) * 8);
#pragma unroll
        for (int f = 0; f < 4; ++f) {
            int ir = cbase + f * 16 + r;
            sh8 bk = *(const sh8*)(sKT + ir * P + ((kq + (ir >> 2)) & 15) * 8);
            acc[f] = __builtin_amdgcn_mfma_f32_16x16x32_bf16(a, bk, acc[f], 0, 0, 0);
            if (doK) kz[f] = __builtin_amdgcn_mfma_f32_16x16x32_bf16(ones, bk, kz[f], 0, 0, 0);
        }
    }
    unsigned short* out = SB + ((size_t)(b * NC + c)) * D * D;
#pragma unroll
    for (int f = 0; f < 4; ++f) {
        int i = cbase + f * 16 + r;
#pragma unroll
        for (int e = 0; e < 4; ++e) {
            int v = vs * 64 + rbase + q * 4 + e;
            out[(size_t)v * D + i] = f2bf(acc[f][e]);
        }
    }
    if (doK && q == 0 && vs == 0) {
#pragma unroll
        for (int f = 0; f < 4; ++f)
            Ksum[((size_t)(b * NC + c)) * D + cbase + f * 16 + r] = kz[f][0];
    }
}

// ---------------------------------------------------------------------------
// k_scan: exclusive prefix over chunks, prefetch-all-32. (unchanged from R8)
// ---------------------------------------------------------------------------
__global__ __launch_bounds__(256) void k_scan(unsigned short* __restrict__ SB,
                                              float* __restrict__ Ksum) {
    const int SD = D * D;
    int idx = blockIdx.x * 256 + threadIdx.x;
    if (idx < Bc * SD) {
        int b = idx / SD, e = idx % SD;
        size_t off0 = (size_t)b * NC * SD + e;
        unsigned short vals[NC];
#pragma unroll
        for (int c = 0; c < NC; ++c) vals[c] = SB[off0 + (size_t)c * SD];
        float run = 0.0f;
#pragma unroll
        for (int c = 0; c < NC; ++c) {
            SB[off0 + (size_t)c * SD] = f2bf(run);
            run += bf2f(vals[c]);
        }
    } else if (idx < Bc * SD + Bc * D) {
        int rr = idx - Bc * SD;
        int b = rr >> 7, i = rr & 127;
        size_t off0 = (size_t)b * NC * D + i;
        float vals[NC];
#pragma unroll
        for (int c = 0; c < NC; ++c) vals[c] = Ksum[off0 + (size_t)c * D];
        float run = 0.0f;
#pragma unroll
        for (int c = 0; c < NC; ++c) {
            Ksum[off0 + (size_t)c * D] = run;
            run += vals[c];
        }
    }
}

// ---------------------------------------------------------------------------
// k_out (NC,B,4), rows split 4x32, 512 thr (8 waves: rbase=(w&1)*16,
// col quarter cq=w>>1).  phiQ in regs; phiK + V^T staged in LDS; GEMM4
// B-frags direct from SB; register z.  2 syncs.  LDS ~78 KB.
// ---------------------------------------------------------------------------
__global__ __launch_bounds__(512) void k_out(
    const float* __restrict__ Q, const float* __restrict__ K,
    const float* __restrict__ V, const unsigned short* __restrict__ SB,
    const float* __restrict__ Ksum, float* __restrict__ Out) {
    const int c = blockIdx.x, b = blockIdx.y, rs = blockIdx.z;  // rs 0..3
    const int tid = threadIdx.x;
    __shared__ __align__(16) unsigned short sK[128 * P];   // phiK rows
    __shared__ __align__(16) unsigned short sVT[128 * P];  // V^T swizzled
    __shared__ __align__(16) unsigned short sAm[32 * P];   // masked A
    const size_t base  = ((size_t)b * L + (size_t)c * C) * D;
    const size_t tbase = ((size_t)(b * NC + c)) * (size_t)D * D;
    const size_t kb    = ((size_t)(b * NC + c)) * D;

    const int w = tid >> 6, lane = tid & 63;
    const int r = lane & 15, q = lane >> 4;
    const int rbase = (w & 1) * 16;
    const int cq = w >> 1, cbase = cq * 32;

    // ---- phiQ A-frags to registers (phi once; reused GEMM2 + GEMM4) ----
    sh8 aq[4];
    {
        const float* qrow = Q + base + (size_t)(rs * 32 + rbase + r) * D;
#pragma unroll
        for (int ks = 0; ks < 4; ++ks) aq[ks] = ldphi8(qrow + ks * 32 + q * 8);
    }

    // ---- stage phiK rows (4096 float4, coalesced) ----
#pragma unroll
    for (int k = 0; k < 8; ++k) {
        int fi = tid + 512 * k;
        int row = fi >> 5, c4 = fi & 31;
        float4 kd = *(const float4*)(K + base + (size_t)row * D + c4 * 4);
        uint2 pk; pk.x = packbf(phi(kd.x), phi(kd.y)); pk.y = packbf(phi(kd.z), phi(kd.w));
        *(uint2*)(sK + row * P + c4 * 4) = pk;
    }
    // ---- stage V^T swizzled (4096 float4, coalesced) ----
#pragma unroll
    for (int k = 0; k < 8; ++k) {
        int fi = tid + 512 * k;
        int l = fi >> 5, i4 = fi & 31;
        float4 vd = *(const float4*)(V + base + (size_t)l * D + i4 * 4);
        int blk = (((l >> 3) + i4) & 15) * 8 + (l & 7);
        sVT[(i4 * 4 + 0) * P + blk] = f2bf(vd.x);
        sVT[(i4 * 4 + 1) * P + blk] = f2bf(vd.y);
        sVT[(i4 * 4 + 2) * P + blk] = f2bf(vd.z);
        sVT[(i4 * 4 + 3) * P + blk] = f2bf(vd.w);
    }
    __syncthreads();                       // S1: sK + sVT ready

    // ---- GEMM2: A = phiQ phiK^T (B-frags from LDS) ----
    f4 a2[2];
    a2[0] = {0.f,0.f,0.f,0.f}; a2[1] = {0.f,0.f,0.f,0.f};
#pragma unroll
    for (int ks = 0; ks < 4; ++ks) {
#pragma unroll
        for (int f = 0; f < 2; ++f) {
            sh8 bb = *(const sh8*)(sK + (cbase + f * 16 + r) * P + ks * 32 + q * 8);
            a2[f] = __builtin_amdgcn_mfma_f32_16x16x32_bf16(aq[ks], bb, a2[f], 0, 0, 0);
        }
    }
    // causal mask -> sAm bf16
#pragma unroll
    for (int f = 0; f < 2; ++f) {
        int j = cbase + f * 16 + r;
#pragma unroll
        for (int e = 0; e < 4; ++e) {
            int lr = rbase + q * 4 + e;
            sAm[lr * P + j] = f2bf((j <= rs * 32 + lr) ? a2[f][e] : 0.f);
        }
    }
    __syncthreads();                       // S2: sAm ready

    // ---- GEMM3: acc = Am @ V (+ rowsum z via ones-B) ----
    f4 acc[2], zacc = {0.f,0.f,0.f,0.f};
    acc[0] = {0.f,0.f,0.f,0.f}; acc[1] = {0.f,0.f,0.f,0.f};
    const sh8 ones = splat1();
#pragma unroll
    for (int ks = 0; ks < 4; ++ks) {
        int kq = ks * 4 + q;
        sh8 am = *(const sh8*)(sAm + (rbase + r) * P + ks * 32 + q * 8);
#pragma unroll
        for (int f = 0; f < 2; ++f) {
            int vr = cbase + f * 16 + r;
            sh8 bv = *(const sh8*)(sVT + vr * P + ((kq + (vr >> 2)) & 15) * 8);
            acc[f] = __builtin_amdgcn_mfma_f32_16x16x32_bf16(am, bv, acc[f], 0, 0, 0);
        }
        zacc = __builtin_amdgcn_mfma_f32_16x16x32_bf16(am, ones, zacc, 0, 0, 0);
    }

    // ---- GEMM4: acc += phiQ @ S_prev, B-frags direct from SB bf16;
    //      + kprev z (r-invariant frags from Ksum, L2-hot) ----
    {
        const unsigned short* srow0 = SB + tbase + (size_t)(cbase + r) * D;
        const unsigned short* srow1 = SB + tbase + (size_t)(cbase + 16 + r) * D;
#pragma unroll
        for (int ks = 0; ks < 4; ++ks) {
            sh8 bs0 = *(const sh8*)(srow0 + ks * 32 + q * 8);
            sh8 bs1 = *(const sh8*)(srow1 + ks * 32 + q * 8);
            float4 f0 = *(const float4*)(Ksum + kb + ks * 32 + q * 8);
            float4 f1 = *(const float4*)(Ksum + kb + ks * 32 + q * 8 + 4);
            sh8 bz;
            bz[0] = (short)f2bf(f0.x); bz[1] = (short)f2bf(f0.y);
            bz[2] = (short)f2bf(f0.z); bz[3] = (short)f2bf(f0.w);
            bz[4] = (short)f2bf(f1.x); bz[5] = (short)f2bf(f1.y);
            bz[6] = (short)f2bf(f1.z); bz[7] = (short)f2bf(f1.w);
            acc[0] = __builtin_amdgcn_mfma_f32_16x16x32_bf16(aq[ks], bs0, acc[0], 0, 0, 0);
            acc[1] = __builtin_amdgcn_mfma_f32_16x16x32_bf16(aq[ks], bs1, acc[1], 0, 0, 0);
            zacc   = __builtin_amdgcn_mfma_f32_16x16x32_bf16(aq[ks], bz, zacc, 0, 0, 0);
        }
    }

    // ---- normalize + store: zacc[e] = z(row rbase+q*4+e) in every lane ----
#pragma unroll
    for (int e = 0; e < 4; ++e) {
        int lr = rbase + q * 4 + e;
        float rz = 1.0f / (zacc[e] + EPS);
#pragma unroll
        for (int f = 0; f < 2; ++f) {
            int v = cbase + f * 16 + r;
            Out[base + (size_t)(rs * 32 + lr) * D + v] = acc[f][e] * rz;
        }
    }
}

extern "C" void kernel_launch(void* const* d_in, const int* in_sizes, int n_in,
                              void* d_out, int out_size, void* d_ws, size_t ws_size,
                              hipStream_t stream) {
    const float* Q = (const float*)d_in[0];
    const float* K = (const float*)d_in[1];
    const float* V = (const float*)d_in[2];
    float* Out = (float*)d_out;
    unsigned short* SBw = (unsigned short*)d_ws;                        // 2 MB
    float* Ksum = (float*)((char*)d_ws + (size_t)Bc * NC * D * D * 2);  // 32 KB

    k1<<<dim3(NC, Bc, 2), 512, 0, stream>>>(K, V, SBw, Ksum);
    int total = Bc * D * D + Bc * D;
    k_scan<<<dim3((total + 255) / 256), 256, 0, stream>>>(SBw, Ksum);
    k_out<<<dim3(NC, Bc, 4), 512, 0, stream>>>(Q, K, V, SBw, Ksum, Out);
}